// Round 5
// baseline (349.954 us; speedup 1.0000x reference)
//
#include <hip/hip_runtime.h>

// Hyperbolic_Lines: out = sum_i acosh(1 + d2_i)^2,
//   d2_i = ||y_i||^2 - (y_i . w)^2 / ||w||^2
// Streaming reduction over y [N=500000, D=128] f32 (256 MB read).
// HBM floor ~41 us; y (244 MiB) can sit in 256 MiB L3 -> latency-limited,
// so unroll to 4 rows / wave-iteration for MLP (2 independent dwordx4 loads,
// 4 interleaved shuffle-reduce chains).

#define TPB 256
#define NBLOCKS 2048

__device__ __forceinline__ float dot4(const float4 a, const float4 b) {
    return fmaf(a.x, b.x, fmaf(a.y, b.y, fmaf(a.z, b.z, a.w * b.w)));
}

__global__ __launch_bounds__(TPB) void hyp_partial(const float* __restrict__ w,
                                                   const float* __restrict__ y,
                                                   float* __restrict__ partial,
                                                   int nquads, int rows) {
    const int lane = threadIdx.x & 63;   // lane in wave
    const int hl   = lane & 31;          // lane within 32-half
    const int wid  = blockIdx.x * (TPB / 64) + (threadIdx.x >> 6);
    const int nw   = gridDim.x * (TPB / 64);

    // w fragment: columns hl*4 .. hl*4+3 (replicated in both 32-halves)
    const float4 wv = *reinterpret_cast<const float4*>(w + hl * 4);

    // ||w||^2 via 5-step butterfly within each 32-lane half
    float nw2 = dot4(wv, wv);
#pragma unroll
    for (int m = 1; m <= 16; m <<= 1) nw2 += __shfl_xor(nw2, m);
    const float inv_nw2 = 1.0f / nw2;

    float acc = 0.0f;

    // each wave: 4 rows (= 2 KB) per iteration; rows 4q+{0,1} from load A
    // (lanes 0-31 / 32-63), rows 4q+{2,3} from load B.
    for (int q = wid; q < nquads; q += nw) {
        const float* base = y + (size_t)q * 512 + lane * 4;
        const float4 va = *reinterpret_cast<const float4*>(base);
        const float4 vb = *reinterpret_cast<const float4*>(base + 256);
        float s1a = dot4(va, va), s2a = dot4(va, wv);
        float s1b = dot4(vb, vb), s2b = dot4(vb, wv);
#pragma unroll
        for (int m = 1; m <= 16; m <<= 1) {  // 4 independent chains -> ILP
            s1a += __shfl_xor(s1a, m);
            s2a += __shfl_xor(s2a, m);
            s1b += __shfl_xor(s1b, m);
            s2b += __shfl_xor(s2b, m);
        }
        const float xa = fmaf(-s2a * inv_nw2, s2a, s1a) + 1.0f;
        const float xb = fmaf(-s2b * inv_nw2, s2b, s1b) + 1.0f;
        const float aa = __logf(xa + sqrtf(fmaf(xa, xa, -1.0f)));
        const float ab = __logf(xb + sqrtf(fmaf(xb, xb, -1.0f)));
        acc += (hl == 0) ? fmaf(aa, aa, ab * ab) : 0.0f;  // 1 lane per half
    }

    // trailing rows (rows % 4 != 0; not hit for N=500000)
    if (wid == 0) {
        for (int r = nquads * 4; r < rows; ++r) {
            const float4 v =
                *reinterpret_cast<const float4*>(y + (size_t)r * 128 + hl * 4);
            float s1 = dot4(v, v), s2 = dot4(v, wv);
#pragma unroll
            for (int m = 1; m <= 16; m <<= 1) {
                s1 += __shfl_xor(s1, m);
                s2 += __shfl_xor(s2, m);
            }
            const float x = fmaf(-s2 * inv_nw2, s2, s1) + 1.0f;
            const float a = __logf(x + sqrtf(fmaf(x, x, -1.0f)));
            acc += (lane == 0) ? a * a : 0.0f;  // only half 0 contributes
        }
    }

    // wave reduce (all 64 lanes; sums both halves' contributions)
#pragma unroll
    for (int m = 1; m <= 32; m <<= 1) acc += __shfl_xor(acc, m);

    __shared__ float wacc[TPB / 64];
    if (lane == 0) wacc[threadIdx.x >> 6] = acc;
    __syncthreads();
    if (threadIdx.x == 0) {
        float b = 0.0f;
#pragma unroll
        for (int i = 0; i < TPB / 64; ++i) b += wacc[i];
        partial[blockIdx.x] = b;
    }
}

__global__ __launch_bounds__(256) void hyp_reduce(const float* __restrict__ partial,
                                                  int n, float* __restrict__ out) {
    __shared__ double sh[256];
    double s = 0.0;
    for (int i = threadIdx.x; i < n; i += 256) s += (double)partial[i];
    sh[threadIdx.x] = s;
    __syncthreads();
    for (int off = 128; off > 0; off >>= 1) {
        if (threadIdx.x < off) sh[threadIdx.x] += sh[threadIdx.x + off];
        __syncthreads();
    }
    if (threadIdx.x == 0) out[0] = (float)sh[0];
}

extern "C" void kernel_launch(void* const* d_in, const int* in_sizes, int n_in,
                              void* d_out, int out_size, void* d_ws, size_t ws_size,
                              hipStream_t stream) {
    const float* w = (const float*)d_in[0];   // [128]
    const float* y = (const float*)d_in[1];   // [N,128]
    float* out = (float*)d_out;               // [1]
    float* partial = (float*)d_ws;            // NBLOCKS floats

    const int rows   = in_sizes[1] / 128;
    const int nquads = rows / 4;

    hyp_partial<<<NBLOCKS, TPB, 0, stream>>>(w, y, partial, nquads, rows);
    hyp_reduce<<<1, 256, 0, stream>>>(partial, NBLOCKS, out);
}

// Round 7
// 343.284 us; speedup vs baseline: 1.0194x; 1.0194x over previous
//
#include <hip/hip_runtime.h>

// Hyperbolic_Lines: out = sum_i acosh(1 + d2_i)^2,
//   d2_i = ||y_i||^2 - (y_i . w)^2 / ||w||^2
// Streaming reduction over y [N=500000, D=128] f32 (256 MB read).
// Repeat of R2's 2-row kernel (best measured, 343.6 us total) to establish
// the cross-session noise band. R5's 4-row MLP variant measured 349.9 us
// -> not latency-limited; BW-bound at the ~41 us HBM/L3 floor, with the
// ~300 us residual being harness re-poison fills (1 GB @ ~153 us each).

#define TPB 256
#define NBLOCKS 2048

__global__ __launch_bounds__(TPB) void hyp_partial(const float* __restrict__ w,
                                                   const float* __restrict__ y,
                                                   float* __restrict__ partial,
                                                   int npairs, int rows) {
    const int lane = threadIdx.x & 63;   // lane in wave
    const int hl   = lane & 31;          // lane within 32-half
    const int wid  = blockIdx.x * (TPB / 64) + (threadIdx.x >> 6);
    const int nw   = gridDim.x * (TPB / 64);

    // w fragment: columns hl*4 .. hl*4+3 (replicated in both 32-halves)
    const float4 wv = *reinterpret_cast<const float4*>(w + hl * 4);

    // ||w||^2 via 5-step butterfly within each 32-lane half
    float nw2 = fmaf(wv.x, wv.x, fmaf(wv.y, wv.y, fmaf(wv.z, wv.z, wv.w * wv.w)));
#pragma unroll
    for (int m = 1; m <= 16; m <<= 1) nw2 += __shfl_xor(nw2, m);
    const float inv_nw2 = 1.0f / nw2;

    float acc = 0.0f;

    // each wave: 2 rows (=1 KB) per iteration, fully coalesced float4 loads
    for (int p = wid; p < npairs; p += nw) {
        const float4 v =
            *reinterpret_cast<const float4*>(y + (size_t)p * 256 + lane * 4);
        float s1 = fmaf(v.x, v.x, fmaf(v.y, v.y, fmaf(v.z, v.z, v.w * v.w)));
        float s2 = fmaf(v.x, wv.x, fmaf(v.y, wv.y, fmaf(v.z, wv.z, v.w * wv.w)));
#pragma unroll
        for (int m = 1; m <= 16; m <<= 1) {  // reduce within each 32-half
            s1 += __shfl_xor(s1, m);
            s2 += __shfl_xor(s2, m);
        }
        const float d2 = s1 - s2 * s2 * inv_nw2;
        const float x  = 1.0f + d2;
        const float a  = __logf(x + sqrtf(fmaf(x, x, -1.0f)));
        acc += (hl == 0) ? a * a : 0.0f;  // one lane per half contributes
    }

    // odd trailing row (not hit for N=500000, kept for generality)
    if ((rows & 1) && wid == 0) {
        const float4 v =
            *reinterpret_cast<const float4*>(y + (size_t)(rows - 1) * 128 + hl * 4);
        float s1 = fmaf(v.x, v.x, fmaf(v.y, v.y, fmaf(v.z, v.z, v.w * v.w)));
        float s2 = fmaf(v.x, wv.x, fmaf(v.y, wv.y, fmaf(v.z, wv.z, v.w * wv.w)));
#pragma unroll
        for (int m = 1; m <= 16; m <<= 1) {
            s1 += __shfl_xor(s1, m);
            s2 += __shfl_xor(s2, m);
        }
        const float d2 = s1 - s2 * s2 * inv_nw2;
        const float x  = 1.0f + d2;
        const float a  = __logf(x + sqrtf(fmaf(x, x, -1.0f)));
        acc += (lane == 0) ? a * a : 0.0f;
    }

    // wave reduce (all 64 lanes; sums both halves' contributions)
#pragma unroll
    for (int m = 1; m <= 32; m <<= 1) acc += __shfl_xor(acc, m);

    __shared__ float wacc[TPB / 64];
    if (lane == 0) wacc[threadIdx.x >> 6] = acc;
    __syncthreads();
    if (threadIdx.x == 0) {
        float b = 0.0f;
#pragma unroll
        for (int i = 0; i < TPB / 64; ++i) b += wacc[i];
        partial[blockIdx.x] = b;
    }
}

__global__ __launch_bounds__(256) void hyp_reduce(const float* __restrict__ partial,
                                                  int n, float* __restrict__ out) {
    __shared__ double sh[256];
    double s = 0.0;
    for (int i = threadIdx.x; i < n; i += 256) s += (double)partial[i];
    sh[threadIdx.x] = s;
    __syncthreads();
    for (int off = 128; off > 0; off >>= 1) {
        if (threadIdx.x < off) sh[threadIdx.x] += sh[threadIdx.x + off];
        __syncthreads();
    }
    if (threadIdx.x == 0) out[0] = (float)sh[0];
}

extern "C" void kernel_launch(void* const* d_in, const int* in_sizes, int n_in,
                              void* d_out, int out_size, void* d_ws, size_t ws_size,
                              hipStream_t stream) {
    const float* w = (const float*)d_in[0];   // [128]
    const float* y = (const float*)d_in[1];   // [N,128]
    float* out = (float*)d_out;               // [1]
    float* partial = (float*)d_ws;            // NBLOCKS floats

    const int rows   = in_sizes[1] / 128;
    const int npairs = rows / 2;

    hyp_partial<<<NBLOCKS, TPB, 0, stream>>>(w, y, partial, npairs, rows);
    hyp_reduce<<<1, 256, 0, stream>>>(partial, NBLOCKS, out);
}